// Round 6
// baseline (44.605 us; speedup 1.0000x reference)
//
#include <hip/hip_runtime.h>
#include <math.h>

// Problem constants
#define BB   8
#define NB   81
#define HW   76800
#define HW4  19200
#define EPS  1e-10f

#define NBLK 64            // all co-resident (64*16 waves << 8192 slots)
#define NTHR 1024
#define LUTN 512

// ws float-index layout. Cross-phase slots written ONLY via atomicExch
// (coherent point), read via agent-scope atomic loads. Counters memset to 0.
#define ST_OFF  0                 // [64][5]: sd, sd2, ssq, cnt, maxT
#define DA_OFF  320               // [64] dirA block sums
#define CA_OFF  384               // [8][82] int bits: per-slot MAX valid target
#define CB_OFF  1040              // [8][82] int bits: per-slot MIN valid target
#define CNT_OFF 1696              // 2 uints: c1 (phase barrier), c2 (winner ticket)

__device__ __forceinline__ int probe_mode(const void* mask, int tid) {
    unsigned pv = ((const unsigned*)mask)[tid & 63];
    bool alli = __all(pv == 0u || pv == 1u);
    bool allf = __all(pv == 0u || pv == 0x3F800000u);
    return alli ? 1 : (allf ? 2 : 0);      // 1=int32, 2=float, 0=byte
}

__device__ __forceinline__ void mask4(const void* mask, int mode, int widx,
                                      int& m0, int& m1, int& m2, int& m3) {
    if (mode == 1)      { uint4  u = ((const uint4*) mask)[widx]; m0 = u.x; m1 = u.y; m2 = u.z; m3 = u.w; }
    else if (mode == 2) { float4 f = ((const float4*)mask)[widx]; m0 = f.x != 0.f; m1 = f.y != 0.f; m2 = f.z != 0.f; m3 = f.w != 0.f; }
    else { unsigned um = ((const unsigned*)mask)[widx];
           m0 = um & 0xFF; m1 = (um >> 8) & 0xFF; m2 = (um >> 16) & 0xFF; m3 = (um >> 24) & 0xFF; }
}

__device__ __forceinline__ float bsum1024(float v, float* red) {
    int t = threadIdx.x;
    red[t] = v; __syncthreads();
    for (int s = 512; s > 0; s >>= 1) { if (t < s) red[t] += red[t + s]; __syncthreads(); }
    float r = red[0]; __syncthreads();
    return r;
}
__device__ __forceinline__ float bmax1024(float v, float* red) {
    int t = threadIdx.x;
    red[t] = v; __syncthreads();
    for (int s = 512; s > 0; s >>= 1) { if (t < s) red[t] = fmaxf(red[t], red[t + s]); __syncthreads(); }
    float r = red[0]; __syncthreads();
    return r;
}

__device__ __forceinline__ float aload(const float* p) {
    return __hip_atomic_load(p, __ATOMIC_RELAXED, __HIP_MEMORY_SCOPE_AGENT);
}
__device__ __forceinline__ int aloadi(const int* p) {
    return __hip_atomic_load(p, __ATOMIC_RELAXED, __HIP_MEMORY_SCOPE_AGENT);
}

// ---------------------------------------------------------------------------
// One kernel: phase 0 (stats + maxT) -> spin barrier -> phase 1 (chamfer)
// -> winner ticket -> finalize. Counters pre-zeroed by an 8-byte memset node.
__global__ __launch_bounds__(NTHR, 1) void k_fused(const float* __restrict__ pred,
                                                   const float* __restrict__ tgt,
                                                   const float* __restrict__ bins,
                                                   const void*  __restrict__ mask,
                                                   float* __restrict__ ws,
                                                   float* __restrict__ out) {
    __shared__ float red[NTHR];
    __shared__ float sraw[NB], ssrt[NB];
    __shared__ int   lut[LUTN];
    __shared__ int   iA[82], iB[82];
    __shared__ unsigned s_tick;
    // winner-phase scratch
    __shared__ float allb[BB * NB], sbAll[BB * NB];
    __shared__ float fA[BB * 82], fB[BB * 82];
    __shared__ float tmpR[BB][82];
    __shared__ float out8[BB];

    int tid = threadIdx.x, bid = blockIdx.x;
    int b = bid >> 3, c = bid & 7;
    int mode = probe_mode(mask, tid);

    // block 8: re-init candidate sentinels via coherent-point exchanges.
    // Other blocks touch CA/CB only after the c1 barrier -> ordered.
    if (bid == 8) {
        for (int i = tid; i < BB * 82; i += NTHR) {
            atomicExch((int*)ws + CA_OFF + i, 0xFF800000);   // -inf bits
            atomicExch((int*)ws + CB_OFF + i, 0x7F800000);   // +inf bits
        }
    }

    // ================= Phase 0: stats + masked max =================
    const float4* p4p = (const float4*)(pred + (size_t)b * HW);
    const float4* t4p = (const float4*)(tgt  + (size_t)b * HW);
    float sd = 0.f, sd2 = 0.f, ssq = 0.f, cnt = 0.f, mt = 0.f;
    for (int i = c * NTHR + tid; i < HW4; i += 8 * NTHR) {
        float4 p = p4p[i], t = t4p[i];
        int m0, m1, m2, m3;
        mask4(mask, mode, b * HW4 + i, m0, m1, m2, m3);
        if (m0) { float d = __logf((p.x + EPS) / (t.x + EPS)); sd += d; sd2 += d*d; float e = p.x - t.x; ssq += e*e; cnt += 1.f; mt = fmaxf(mt, t.x); }
        if (m1) { float d = __logf((p.y + EPS) / (t.y + EPS)); sd += d; sd2 += d*d; float e = p.y - t.y; ssq += e*e; cnt += 1.f; mt = fmaxf(mt, t.y); }
        if (m2) { float d = __logf((p.z + EPS) / (t.z + EPS)); sd += d; sd2 += d*d; float e = p.z - t.z; ssq += e*e; cnt += 1.f; mt = fmaxf(mt, t.z); }
        if (m3) { float d = __logf((p.w + EPS) / (t.w + EPS)); sd += d; sd2 += d*d; float e = p.w - t.w; ssq += e*e; cnt += 1.f; mt = fmaxf(mt, t.w); }
    }
    float r0 = bsum1024(sd, red);
    float r1 = bsum1024(sd2, red);
    float r2 = bsum1024(ssq, red);
    float r3 = bsum1024(cnt, red);
    float r4 = bmax1024(mt, red);
    if (tid == 0) {
        atomicExch(&ws[ST_OFF + bid * 5 + 0], r0);
        atomicExch(&ws[ST_OFF + bid * 5 + 1], r1);
        atomicExch(&ws[ST_OFF + bid * 5 + 2], r2);
        atomicExch(&ws[ST_OFF + bid * 5 + 3], r3);
        atomicExch(&ws[ST_OFF + bid * 5 + 4], r4);
    }

    // ---- spin barrier: each wave drains its own vmem, then tid0 arrives ----
    asm volatile("s_waitcnt vmcnt(0)" ::: "memory");
    __syncthreads();
    if (tid == 0) {
        atomicAdd((unsigned*)ws + CNT_OFF, 1u);
        while (__hip_atomic_load((const unsigned*)ws + CNT_OFF,
                                 __ATOMIC_RELAXED, __HIP_MEMORY_SCOPE_AGENT) < (unsigned)NBLK)
            __builtin_amdgcn_s_sleep(2);
    }
    __syncthreads();

    // ================= Phase 1: chamfer (pad now known) =================
    float mp = (tid < NBLK) ? aload(&ws[ST_OFF + tid * 5 + 4]) : -INFINITY;
    float maxT = bmax1024(mp, red);
    float mb = (tid < BB * NB) ? bins[tid] : -INFINITY;
    float maxB = bmax1024(mb, red);
    float mx = fmaxf(maxT, maxB), mn = fminf(maxT, maxB);
    float pad = mx + (mx - mn) + 1.0f;

    if (tid < NB) sraw[tid] = bins[b * NB + tid];
    __syncthreads();
    if (tid < NB) {
        float v = sraw[tid]; int r = 0;
        for (int k = 0; k < NB; ++k) { float u = sraw[k]; r += (u < v) || (u == v && k < tid); }
        ssrt[r] = v;
    }
    if (tid < 82) { iA[tid] = 0xFF800000; iB[tid] = 0x7F800000; }
    __syncthreads();

    float lo = ssrt[0], hi = ssrt[NB - 1];
    float w = (hi - lo) / (float)LUTN;
    float scale = (hi > lo) ? (float)LUTN / (hi - lo) : 0.f;
    if (tid < LUTN) {
        float edge = lo + (float)tid * w;
        int l = 0, r = NB;
        while (l < r) { int m = (l + r) >> 1; if (ssrt[m] < edge) l = m + 1; else r = m; }
        lut[tid] = l;
    }
    __syncthreads();

    float dA = 0.f;
    for (int i = c * NTHR + tid; i < HW4; i += 8 * NTHR) {   // same mapping as phase 0 -> L2-hot
        float4 t = t4p[i];
        int m0, m1, m2, m3;
        mask4(mask, mode, b * HW4 + i, m0, m1, m2, m3);
        float tv[4] = { t.x, t.y, t.z, t.w };
        int   mv[4] = { m0, m1, m2, m3 };
#pragma unroll
        for (int e = 0; e < 4; ++e) {
            if (!mv[e]) continue;
            float v = tv[e];
            int q = (int)((v - lo) * scale);
            q = q < 0 ? 0 : (q > LUTN - 1 ? LUTN - 1 : q);
            int s = lut[q];
            while (s < NB && ssrt[s] <= v) ++s;
            while (s > 0 && ssrt[s - 1] > v) --s;
            float lof = (s > 0)  ? ssrt[s - 1] : -INFINITY;
            float hif = (s < NB) ? ssrt[s]     : pad;        // pad is the upper flank
            float dl = v - lof, dh = hif - v;
            dA += fminf(dl * dl, dh * dh);
            int bits = __float_as_int(v);
            atomicMax(&iA[s], bits);
            atomicMin(&iB[s], bits);
        }
    }

    float rA = bsum1024(dA, red);            // syncs inside -> iA/iB settled
    if (tid < 82) {
        atomicMax((int*)ws + CA_OFF + b * 82 + tid, iA[tid]);
        atomicMin((int*)ws + CB_OFF + b * 82 + tid, iB[tid]);
    }
    if (tid == 0) atomicExch(&ws[DA_OFF + bid], rA);

    // winner ticket (drain own RMWs first)
    asm volatile("s_waitcnt vmcnt(0)" ::: "memory");
    __syncthreads();
    if (tid == 0) s_tick = atomicAdd((unsigned*)ws + CNT_OFF + 1, 1u);
    __syncthreads();
    if (s_tick != NBLK - 1) return;

    // ================= Winner: fold + dirB sweep + output =================
    if (tid < BB * NB) allb[tid] = bins[tid];
    __syncthreads();
    if (tid < BB * NB) {
        int b2 = tid / NB, j = tid - b2 * NB;
        float v = allb[tid]; int r = 0;
        for (int k = 0; k < NB; ++k) { float u = allb[b2 * NB + k]; r += (u < v) || (u == v && k < j); }
        sbAll[b2 * NB + r] = v;
    }
    if (tid < BB * 82) {
        fA[tid] = __int_as_float(aloadi((int*)ws + CA_OFF + tid));
        fB[tid] = __int_as_float(aloadi((int*)ws + CB_OFF + tid));
    }
    __syncthreads();

    if (tid < BB) {
        const float* SBb = &sbAll[tid * NB];
        float cntb = 0.f;
        for (int j = 0; j < 8; ++j) cntb += aload(&ws[ST_OFF + (tid * 8 + j) * 5 + 3]);
        bool anyInv = (cntb != (float)HW);
        float rmin = anyInv ? pad : INFINITY;
        { float d = rmin - pad; tmpR[tid][81] = d * d; }
        for (int k = NB - 1; k >= 0; --k) {
            rmin = fminf(rmin, fB[tid * 82 + k + 1]);
            float d = rmin - SBb[k];
            tmpR[tid][k] = d * d;
        }
        float lmax = -INFINITY, sb = 0.f;
        for (int k = 0; k <= NB; ++k) {
            lmax = fmaxf(lmax, fA[tid * 82 + k]);
            float sk = (k < NB) ? SBb[k] : pad;
            float d = sk - lmax;
            sb += fminf(d * d, tmpR[tid][k]);
        }
        out8[tid] = sb;
    }

    float v0 = 0.f, v1 = 0.f, v2 = 0.f, v3 = 0.f, va = 0.f;
    if (tid < NBLK) {
        v0 = aload(&ws[ST_OFF + tid * 5 + 0]);
        v1 = aload(&ws[ST_OFF + tid * 5 + 1]);
        v2 = aload(&ws[ST_OFF + tid * 5 + 2]);
        v3 = aload(&ws[ST_OFF + tid * 5 + 3]);
        va = aload(&ws[DA_OFF + tid]);
    }
    float s0 = bsum1024(v0, red);
    float s1 = bsum1024(v1, red);
    float s2 = bsum1024(v2, red);
    float s3 = bsum1024(v3, red);
    float sa = bsum1024(va, red);

    if (tid == 0) {
        float sumB = 0.f;
        for (int i = 0; i < BB; ++i) sumB += out8[i];
        float m1 = s0 / s3, m2 = s1 / s3;
        float silog = 10.0f * sqrtf(fmaxf(m2 - 0.85f * m1 * m1, 0.0f));
        float l2 = sqrtf(s2 / s3);
        float chamfer = (sa + sumB) / (float)BB;
        out[0] = l2 + silog + chamfer;
    }
}

// ---------------------------------------------------------------------------
extern "C" void kernel_launch(void* const* d_in, const int* in_sizes, int n_in,
                              void* d_out, int out_size, void* d_ws, size_t ws_size,
                              hipStream_t stream) {
    (void)in_sizes; (void)n_in; (void)out_size; (void)ws_size;
    const float* pred = (const float*)d_in[0];
    const float* tgt  = (const float*)d_in[1];
    const float* bins = (const float*)d_in[2];
    const void*  mask = d_in[3];
    float* ws  = (float*)d_ws;
    float* out = (float*)d_out;

    // zero the two coordination counters (graph-capturable async memset)
    hipMemsetAsync((char*)d_ws + CNT_OFF * sizeof(float), 0, 2 * sizeof(unsigned), stream);
    k_fused<<<NBLK, NTHR, 0, stream>>>(pred, tgt, bins, mask, ws, out);
}

// Round 7
// 35.379 us; speedup vs baseline: 1.2608x; 1.2608x over previous
//
#include <hip/hip_runtime.h>
#include <math.h>

// Problem constants
#define BB   8
#define NB   81
#define HW   76800
#define HW4  19200
#define EPS  1e-10f

#define NBLK 64
#define NTHR 1024
#define LUTN 512
#define MAGIC 0x5A5A5A5Au

typedef unsigned long long u64;

// ws layout. u64 slots (checksum pairs / packs):
//   PT_U [64]      : per-block maxT pair
//   ST_U [64][4]   : per-block stats packs (sd, sd2, ssq, cnt)
//   DA_U [64]      : per-block dirA-sum pair (published AFTER CA/CB drain -> gate)
// int slots (idempotent monotone merges; poison-tolerant encodings):
//   CA_I [8][82]   : per-slot MAX valid target, raw float bits (poison neg -> loses / -inf)
//   CB_I [8][82]   : per-slot MIN valid target, enc = 0x7FFFFFFF - bits (poison -> +inf)
#define PT_U 0
#define ST_U 64
#define DA_U 320
#define CA_I 768            // int index (= 384 u64 * 2)
#define CB_I 1424

__device__ __forceinline__ u64 pack(float v) {
    unsigned b = __float_as_uint(v);
    return (u64)b | ((u64)(b ^ MAGIC) << 32);
}

// wave-0-only: spin until this lane's pair checks out for ALL 64 lanes
__device__ __forceinline__ float spin_pair(const u64* slot) {
    u64 v;
    for (;;) {
        v = __hip_atomic_load(slot, __ATOMIC_RELAXED, __HIP_MEMORY_SCOPE_AGENT);
        unsigned lo = (unsigned)v, hi = (unsigned)(v >> 32);
        if (__all((lo ^ MAGIC) == hi)) break;
        __builtin_amdgcn_s_sleep(1);
    }
    return __uint_as_float((unsigned)v);
}

__device__ __forceinline__ int probe_mode(const void* mask, int tid) {
    unsigned pv = ((const unsigned*)mask)[tid & 63];
    bool alli = __all(pv == 0u || pv == 1u);
    bool allf = __all(pv == 0u || pv == 0x3F800000u);
    return alli ? 1 : (allf ? 2 : 0);      // 1=int32, 2=float, 0=byte
}

__device__ __forceinline__ void mask4(const void* mask, int mode, int widx,
                                      int& m0, int& m1, int& m2, int& m3) {
    if (mode == 1)      { uint4  u = ((const uint4*) mask)[widx]; m0 = u.x; m1 = u.y; m2 = u.z; m3 = u.w; }
    else if (mode == 2) { float4 f = ((const float4*)mask)[widx]; m0 = f.x != 0.f; m1 = f.y != 0.f; m2 = f.z != 0.f; m3 = f.w != 0.f; }
    else { unsigned um = ((const unsigned*)mask)[widx];
           m0 = um & 0xFF; m1 = (um >> 8) & 0xFF; m2 = (um >> 16) & 0xFF; m3 = (um >> 24) & 0xFF; }
}

__device__ __forceinline__ float bsum1024(float v, float* red) {
    int t = threadIdx.x;
    red[t] = v; __syncthreads();
    for (int s = 512; s > 0; s >>= 1) { if (t < s) red[t] += red[t + s]; __syncthreads(); }
    float r = red[0]; __syncthreads();
    return r;
}
__device__ __forceinline__ float bmax1024(float v, float* red) {
    int t = threadIdx.x;
    red[t] = v; __syncthreads();
    for (int s = 512; s > 0; s >>= 1) { if (t < s) red[t] = fmaxf(red[t], red[t + s]); __syncthreads(); }
    float r = red[0]; __syncthreads();
    return r;
}

// ---------------------------------------------------------------------------
__global__ __launch_bounds__(NTHR, 1) void k_fused(const float* __restrict__ pred,
                                                   const float* __restrict__ tgt,
                                                   const float* __restrict__ bins,
                                                   const void*  __restrict__ mask,
                                                   float* __restrict__ ws,
                                                   float* __restrict__ out) {
    __shared__ float red[NTHR];
    __shared__ float sraw[NB], ssrt[NB];
    __shared__ int   lut[LUTN];
    __shared__ int   iA[82], iB[82];
    __shared__ float s_maxT;
    // finalize scratch (block 0 only)
    __shared__ float allb[BB * NB], sbAll[BB * NB];
    __shared__ float fA[BB * 82], fB[BB * 82];
    __shared__ float tmpR[BB][82];
    __shared__ float out8[BB];
    __shared__ float da64[64], st0[64], st1[64], st2[64], st3[64];

    int tid = threadIdx.x, bid = blockIdx.x;
    int b = bid >> 3, c = bid & 7;
    u64* wsu = (u64*)ws;
    int* wsi = (int*)ws;
    int mode = probe_mode(mask, tid);

    // ================= Phase 0: stats + masked max =================
    const float4* p4p = (const float4*)(pred + (size_t)b * HW);
    const float4* t4p = (const float4*)(tgt  + (size_t)b * HW);
    float sd = 0.f, sd2 = 0.f, ssq = 0.f, cnt = 0.f, mt = 0.f;
    for (int i = c * NTHR + tid; i < HW4; i += 8 * NTHR) {
        float4 p = p4p[i], t = t4p[i];
        int m0, m1, m2, m3;
        mask4(mask, mode, b * HW4 + i, m0, m1, m2, m3);
        if (m0) { float d = __logf((p.x + EPS) / (t.x + EPS)); sd += d; sd2 += d*d; float e = p.x - t.x; ssq += e*e; cnt += 1.f; mt = fmaxf(mt, t.x); }
        if (m1) { float d = __logf((p.y + EPS) / (t.y + EPS)); sd += d; sd2 += d*d; float e = p.y - t.y; ssq += e*e; cnt += 1.f; mt = fmaxf(mt, t.y); }
        if (m2) { float d = __logf((p.z + EPS) / (t.z + EPS)); sd += d; sd2 += d*d; float e = p.z - t.z; ssq += e*e; cnt += 1.f; mt = fmaxf(mt, t.z); }
        if (m3) { float d = __logf((p.w + EPS) / (t.w + EPS)); sd += d; sd2 += d*d; float e = p.w - t.w; ssq += e*e; cnt += 1.f; mt = fmaxf(mt, t.w); }
    }
    float r0 = bsum1024(sd, red);
    float r1 = bsum1024(sd2, red);
    float r2 = bsum1024(ssq, red);
    float r3 = bsum1024(cnt, red);
    float r4 = bmax1024(mt, red);
    if (tid == 0) {
        atomicExch(&wsu[ST_U + bid * 4 + 0], pack(r0));
        atomicExch(&wsu[ST_U + bid * 4 + 1], pack(r1));
        atomicExch(&wsu[ST_U + bid * 4 + 2], pack(r2));
        atomicExch(&wsu[ST_U + bid * 4 + 3], pack(r3));
        asm volatile("s_waitcnt vmcnt(0)" ::: "memory");      // ST at coherent point
        atomicExch(&wsu[PT_U + bid], pack(r4));               // then the gate pair
    }

    // ---- phase barrier: wave 0 spins on all 64 maxT pairs ----
    if (tid < 64) {
        float v = spin_pair(&wsu[PT_U + tid]);
        for (int o = 32; o > 0; o >>= 1) v = fmaxf(v, __shfl_xor(v, o, 64));
        if (tid == 0) s_maxT = v;
    }
    __syncthreads();
    float maxT = s_maxT;
    float mb = (tid < BB * NB) ? bins[tid] : -INFINITY;
    float maxB = bmax1024(mb, red);
    float mx = fmaxf(maxT, maxB), mn = fminf(maxT, maxB);
    float pad = mx + (mx - mn) + 1.0f;

    // ================= Phase 1: chamfer =================
    if (tid < NB) sraw[tid] = bins[b * NB + tid];
    __syncthreads();
    if (tid < NB) {
        float v = sraw[tid]; int r = 0;
        for (int k = 0; k < NB; ++k) { float u = sraw[k]; r += (u < v) || (u == v && k < tid); }
        ssrt[r] = v;
    }
    if (tid < 82) { iA[tid] = 0xFF800000; iB[tid] = 0x7F800000; }
    __syncthreads();

    float lo = ssrt[0], hi = ssrt[NB - 1];
    float w = (hi - lo) / (float)LUTN;
    float scale = (hi > lo) ? (float)LUTN / (hi - lo) : 0.f;
    if (tid < LUTN) {
        float edge = lo + (float)tid * w;
        int l = 0, r = NB;
        while (l < r) { int m = (l + r) >> 1; if (ssrt[m] < edge) l = m + 1; else r = m; }
        lut[tid] = l;
    }
    __syncthreads();

    float dA = 0.f;
    for (int i = c * NTHR + tid; i < HW4; i += 8 * NTHR) {   // same mapping as phase 0 -> cache-hot
        float4 t = t4p[i];
        int m0, m1, m2, m3;
        mask4(mask, mode, b * HW4 + i, m0, m1, m2, m3);
        float tv[4] = { t.x, t.y, t.z, t.w };
        int   mv[4] = { m0, m1, m2, m3 };
#pragma unroll
        for (int e = 0; e < 4; ++e) {
            if (!mv[e]) continue;
            float v = tv[e];
            int q = (int)((v - lo) * scale);
            q = q < 0 ? 0 : (q > LUTN - 1 ? LUTN - 1 : q);
            int s = lut[q];
            while (s < NB && ssrt[s] <= v) ++s;
            while (s > 0 && ssrt[s - 1] > v) --s;
            float lof = (s > 0)  ? ssrt[s - 1] : -INFINITY;
            float hif = (s < NB) ? ssrt[s]     : pad;
            float dl = v - lof, dh = hif - v;
            dA += fminf(dl * dl, dh * dh);
            int bits = __float_as_int(v);
            atomicMax(&iA[s], bits);
            atomicMin(&iB[s], bits);
        }
    }

    float rA = bsum1024(dA, red);            // syncs inside -> iA/iB settled
    // idempotent global merges (order-independent, poison-tolerant encodings)
    if (tid < 82) {
        int a = iA[tid], bm = iB[tid];
        if (a  != 0xFF800000) atomicMax(&wsi[CA_I + b * 82 + tid], a);
        if (bm != 0x7F800000) atomicMax(&wsi[CB_I + b * 82 + tid], 0x7FFFFFFF - bm);
    }
    // every wave drains its OWN vmem -> all this block's merges at coherent point
    asm volatile("s_waitcnt vmcnt(0)" ::: "memory");
    __syncthreads();
    if (tid == 0) atomicExch(&wsu[DA_U + bid], pack(rA));    // gate pair

    if (bid != 0) return;

    // ================= Block 0: finalize =================
    if (tid < 64) {
        da64[tid] = spin_pair(&wsu[DA_U + tid]);             // gates ST + CA/CB too
        st0[tid] = __uint_as_float((unsigned)__hip_atomic_load(&wsu[ST_U + tid * 4 + 0], __ATOMIC_RELAXED, __HIP_MEMORY_SCOPE_AGENT));
        st1[tid] = __uint_as_float((unsigned)__hip_atomic_load(&wsu[ST_U + tid * 4 + 1], __ATOMIC_RELAXED, __HIP_MEMORY_SCOPE_AGENT));
        st2[tid] = __uint_as_float((unsigned)__hip_atomic_load(&wsu[ST_U + tid * 4 + 2], __ATOMIC_RELAXED, __HIP_MEMORY_SCOPE_AGENT));
        st3[tid] = __uint_as_float((unsigned)__hip_atomic_load(&wsu[ST_U + tid * 4 + 3], __ATOMIC_RELAXED, __HIP_MEMORY_SCOPE_AGENT));
    }
    if (tid < BB * NB) allb[tid] = bins[tid];
    __syncthreads();
    if (tid < BB * NB) {
        int b2 = tid / NB, j = tid - b2 * NB;
        float v = allb[tid]; int r = 0;
        for (int k = 0; k < NB; ++k) { float u = allb[b2 * NB + k]; r += (u < v) || (u == v && k < j); }
        sbAll[b2 * NB + r] = v;
    }
    if (tid < BB * 82) {
        int ea = __hip_atomic_load(&wsi[CA_I + tid], __ATOMIC_RELAXED, __HIP_MEMORY_SCOPE_AGENT);
        int eb = __hip_atomic_load(&wsi[CB_I + tid], __ATOMIC_RELAXED, __HIP_MEMORY_SCOPE_AGENT);
        fA[tid] = (ea < 0) ? -INFINITY : __int_as_float(ea);
        fB[tid] = (eb < 0) ?  INFINITY : __int_as_float(0x7FFFFFFF - eb);
    }
    __syncthreads();

    if (tid < BB) {
        const float* SBb = &sbAll[tid * NB];
        float cntb = 0.f;
        for (int j = 0; j < 8; ++j) cntb += st3[tid * 8 + j];
        bool anyInv = (cntb != (float)HW);
        float rmin = anyInv ? pad : INFINITY;
        { float d = rmin - pad; tmpR[tid][81] = d * d; }
        for (int k = NB - 1; k >= 0; --k) {
            rmin = fminf(rmin, fB[tid * 82 + k + 1]);
            float d = rmin - SBb[k];
            tmpR[tid][k] = d * d;
        }
        float lmax = -INFINITY, sb = 0.f;
        for (int k = 0; k <= NB; ++k) {
            lmax = fmaxf(lmax, fA[tid * 82 + k]);
            float sk = (k < NB) ? SBb[k] : pad;
            float d = sk - lmax;
            sb += fminf(d * d, tmpR[tid][k]);
        }
        out8[tid] = sb;
    }
    __syncthreads();

    if (tid == 0) {
        float s0 = 0.f, s1 = 0.f, s2 = 0.f, s3 = 0.f, sa = 0.f;
        for (int i = 0; i < 64; ++i) {        // fixed order -> deterministic
            s0 += st0[i]; s1 += st1[i]; s2 += st2[i]; s3 += st3[i]; sa += da64[i];
        }
        float sumB = 0.f;
        for (int i = 0; i < BB; ++i) sumB += out8[i];
        float m1 = s0 / s3, m2 = s1 / s3;
        float silog = 10.0f * sqrtf(fmaxf(m2 - 0.85f * m1 * m1, 0.0f));
        float l2 = sqrtf(s2 / s3);
        float chamfer = (sa + sumB) / (float)BB;
        out[0] = l2 + silog + chamfer;
    }
}

// ---------------------------------------------------------------------------
extern "C" void kernel_launch(void* const* d_in, const int* in_sizes, int n_in,
                              void* d_out, int out_size, void* d_ws, size_t ws_size,
                              hipStream_t stream) {
    (void)in_sizes; (void)n_in; (void)out_size; (void)ws_size;
    const float* pred = (const float*)d_in[0];
    const float* tgt  = (const float*)d_in[1];
    const float* bins = (const float*)d_in[2];
    const void*  mask = d_in[3];
    float* ws  = (float*)d_ws;
    float* out = (float*)d_out;

    k_fused<<<NBLK, NTHR, 0, stream>>>(pred, tgt, bins, mask, ws, out);
}

// Round 8
// 32.628 us; speedup vs baseline: 1.3671x; 1.0843x over previous
//
#include <hip/hip_runtime.h>
#include <math.h>

// Problem constants
#define BB   8
#define NB   81
#define HW   76800
#define HW4  19200
#define EPS  1e-10f

#define NBLK 256           // 1 block/CU, all co-resident
#define NTHR 1024
#define BPB  32            // blocks per batch (NBLK/BB)
#define LUTN 512
#define MAGIC 0x5A5A5A5Au

typedef unsigned long long u64;

// ws u64 layout (checksum packs; poison/replay tolerant):
#define PT_U 0             // [256] per-block maxT pack
#define ST_U 256           // [256][4] sd, sd2, ssq, cnt packs
#define DA_U 1280          // [256] dirA pack (published last -> gates ST/CA/CB)
// int layout (u64 index 1536 onward); idempotent monotone merges:
#define CA_I 3072          // [8][82] max valid target, raw bits (poison neg loses)
#define CB_I 3728          // [8][82] min valid target, enc 0x7FFFFFFF-bits (poison -> +inf)

__device__ __forceinline__ u64 pack(float v) {
    unsigned b = __float_as_uint(v);
    return (u64)b | ((u64)(b ^ MAGIC) << 32);
}
__device__ __forceinline__ float spin_pair(const u64* slot) {   // wave-collective
    u64 v;
    for (;;) {
        v = __hip_atomic_load(slot, __ATOMIC_RELAXED, __HIP_MEMORY_SCOPE_AGENT);
        unsigned lo = (unsigned)v, hi = (unsigned)(v >> 32);
        if (__all((lo ^ MAGIC) == hi)) break;
        __builtin_amdgcn_s_sleep(1);
    }
    return __uint_as_float((unsigned)v);
}
__device__ __forceinline__ float lo_f(u64 v) { return __uint_as_float((unsigned)v); }
__device__ __forceinline__ u64 aload64(const u64* p) {
    return __hip_atomic_load(p, __ATOMIC_RELAXED, __HIP_MEMORY_SCOPE_AGENT);
}
__device__ __forceinline__ int aloadi(const int* p) {
    return __hip_atomic_load(p, __ATOMIC_RELAXED, __HIP_MEMORY_SCOPE_AGENT);
}

__device__ __forceinline__ int probe_mode(const void* mask, int tid) {
    unsigned pv = ((const unsigned*)mask)[tid & 63];
    bool alli = __all(pv == 0u || pv == 1u);
    bool allf = __all(pv == 0u || pv == 0x3F800000u);
    return alli ? 1 : (allf ? 2 : 0);      // 1=int32, 2=float, 0=byte
}
__device__ __forceinline__ void mask4(const void* mask, int mode, int widx,
                                      int& m0, int& m1, int& m2, int& m3) {
    if (mode == 1)      { uint4  u = ((const uint4*) mask)[widx]; m0 = u.x; m1 = u.y; m2 = u.z; m3 = u.w; }
    else if (mode == 2) { float4 f = ((const float4*)mask)[widx]; m0 = f.x != 0.f; m1 = f.y != 0.f; m2 = f.z != 0.f; m3 = f.w != 0.f; }
    else { unsigned um = ((const unsigned*)mask)[widx];
           m0 = um & 0xFF; m1 = (um >> 8) & 0xFF; m2 = (um >> 16) & 0xFF; m3 = (um >> 24) & 0xFF; }
}

__device__ __forceinline__ float bsum1024(float v, float* red) {
    int t = threadIdx.x;
    red[t] = v; __syncthreads();
    for (int s = 512; s > 0; s >>= 1) { if (t < s) red[t] += red[t + s]; __syncthreads(); }
    float r = red[0]; __syncthreads();
    return r;
}
__device__ __forceinline__ float bmax1024(float v, float* red) {
    int t = threadIdx.x;
    red[t] = v; __syncthreads();
    for (int s = 512; s > 0; s >>= 1) { if (t < s) red[t] = fmaxf(red[t], red[t + s]); __syncthreads(); }
    float r = red[0]; __syncthreads();
    return r;
}

// ---------------------------------------------------------------------------
__global__ __launch_bounds__(NTHR, 1) void k_fused(const float* __restrict__ pred,
                                                   const float* __restrict__ tgt,
                                                   const float* __restrict__ bins,
                                                   const void*  __restrict__ mask,
                                                   float* __restrict__ ws,
                                                   float* __restrict__ out) {
    __shared__ float red[NTHR];
    __shared__ float sraw[NB], ssrt[NB];
    __shared__ int   lut[LUTN];
    __shared__ int   iA[82], iB[82];
    // block-0 finalize scratch
    __shared__ float allb[BB * NB], sbAll[BB * NB];
    __shared__ float fA[BB * 82], fB[BB * 82];
    __shared__ float tmpR[BB][82];
    __shared__ float out8[BB], cntb8[BB];

    int tid = threadIdx.x, bid = blockIdx.x;
    int b = bid >> 5, c = bid & (BPB - 1);
    u64* wsu = (u64*)ws;
    int* wsi = (int*)ws;
    int mode = probe_mode(mask, tid);

    const int idx = c * NTHR + tid;            // <= 1 float4 per thread per pass
    const bool live = (idx < HW4);
    const float4* p4p = (const float4*)(pred + (size_t)b * HW);
    const float4* t4p = (const float4*)(tgt  + (size_t)b * HW);

    // ============ Phase 0: masked max(target) only (cheap) ============
    float mt = 0.f;
    float4 t4 = make_float4(0.f, 0.f, 0.f, 0.f);
    int m0 = 0, m1 = 0, m2 = 0, m3 = 0;
    if (live) {
        t4 = t4p[idx];
        mask4(mask, mode, b * HW4 + idx, m0, m1, m2, m3);
        if (m0) mt = fmaxf(mt, t4.x);
        if (m1) mt = fmaxf(mt, t4.y);
        if (m2) mt = fmaxf(mt, t4.z);
        if (m3) mt = fmaxf(mt, t4.w);
    }
    float r4 = bmax1024(mt, red);
    if (tid == 0) atomicExch(&wsu[PT_U + bid], pack(r4));   // single coherent write

    // ---- phase barrier: waves 0..3 spin on the 256 maxT packs ----
    float ptv = -INFINITY;
    if (tid < NBLK) ptv = spin_pair(&wsu[PT_U + tid]);
    float maxT = bmax1024(ptv, red);                         // barrier inside
    float mb = (tid < BB * NB) ? bins[tid] : -INFINITY;
    float maxB = bmax1024(mb, red);
    float mx = fmaxf(maxT, maxB), mn = fminf(maxT, maxB);
    float pad = mx + (mx - mn) + 1.0f;

    // ============ Phase 1: fused stats + chamfer ============
    if (tid < NB) sraw[tid] = bins[b * NB + tid];
    __syncthreads();
    if (tid < NB) {
        float v = sraw[tid]; int r = 0;
        for (int k = 0; k < NB; ++k) { float u = sraw[k]; r += (u < v) || (u == v && k < tid); }
        ssrt[r] = v;
    }
    if (tid < 82) { iA[tid] = 0xFF800000; iB[tid] = 0x7F800000; }
    __syncthreads();

    float lo = ssrt[0], hi = ssrt[NB - 1];
    float w = (hi - lo) / (float)LUTN;
    float scale = (hi > lo) ? (float)LUTN / (hi - lo) : 0.f;
    if (tid < LUTN) {
        float edge = lo + (float)tid * w;
        int l = 0, r = NB;
        while (l < r) { int m = (l + r) >> 1; if (ssrt[m] < edge) l = m + 1; else r = m; }
        lut[tid] = l;
    }
    __syncthreads();

    float sd = 0.f, sd2 = 0.f, ssq = 0.f, cnt = 0.f, dA = 0.f;
    if (live) {
        float4 p4 = p4p[idx];
        float pv_[4] = { p4.x, p4.y, p4.z, p4.w };
        float tv_[4] = { t4.x, t4.y, t4.z, t4.w };
        int   mv_[4] = { m0, m1, m2, m3 };
#pragma unroll
        for (int e = 0; e < 4; ++e) {
            if (!mv_[e]) continue;
            float t = tv_[e], p = pv_[e];
            float d = __logf((p + EPS) / (t + EPS));
            sd += d; sd2 += d * d;
            float er = p - t; ssq += er * er;
            cnt += 1.f;
            // slot via LUT + refine
            int q = (int)((t - lo) * scale);
            q = q < 0 ? 0 : (q > LUTN - 1 ? LUTN - 1 : q);
            int s = lut[q];
            while (s < NB && ssrt[s] <= t) ++s;
            while (s > 0 && ssrt[s - 1] > t) --s;
            float lof = (s > 0)  ? ssrt[s - 1] : -INFINITY;
            float hif = (s < NB) ? ssrt[s]     : pad;        // exact pad flank
            float dl = t - lof, dh = hif - t;
            dA += fminf(dl * dl, dh * dh);
            int bits = __float_as_int(t);
            atomicMax(&iA[s], bits);
            atomicMin(&iB[s], bits);
        }
    }
    float r0 = bsum1024(sd, red);
    float r1 = bsum1024(sd2, red);
    float r2 = bsum1024(ssq, red);
    float r3 = bsum1024(cnt, red);
    float rA = bsum1024(dA, red);            // syncs inside -> iA/iB settled

    if (tid < 82) {                           // idempotent monotone global merges
        int a = iA[tid], bm = iB[tid];
        if (a  != 0xFF800000) atomicMax(&wsi[CA_I + b * 82 + tid], a);
        if (bm != 0x7F800000) atomicMax(&wsi[CB_I + b * 82 + tid], 0x7FFFFFFF - bm);
    }
    if (tid == 0) {
        atomicExch(&wsu[ST_U + bid * 4 + 0], pack(r0));
        atomicExch(&wsu[ST_U + bid * 4 + 1], pack(r1));
        atomicExch(&wsu[ST_U + bid * 4 + 2], pack(r2));
        atomicExch(&wsu[ST_U + bid * 4 + 3], pack(r3));
    }
    // every wave drains its OWN vmem -> this block's merges are at the
    // coherent point before its gate pack appears
    asm volatile("s_waitcnt vmcnt(0)" ::: "memory");
    __syncthreads();
    if (tid == 0) atomicExch(&wsu[DA_U + bid], pack(rA));    // gate + data

    if (bid != 0) return;

    // ============ Block 0: finalize ============
    float dav = 0.f;
    if (tid < NBLK) dav = spin_pair(&wsu[DA_U + tid]);       // gates everything
    __syncthreads();

    float v0 = 0.f, v1 = 0.f, v2 = 0.f, v3 = 0.f;
    if (tid < NBLK) {
        v0 = lo_f(aload64(&wsu[ST_U + tid * 4 + 0]));
        v1 = lo_f(aload64(&wsu[ST_U + tid * 4 + 1]));
        v2 = lo_f(aload64(&wsu[ST_U + tid * 4 + 2]));
        v3 = lo_f(aload64(&wsu[ST_U + tid * 4 + 3]));
    }
    float s0 = bsum1024(v0, red);
    float s1 = bsum1024(v1, red);
    float s2 = bsum1024(v2, red);
    float s3 = bsum1024(v3, red);
    float sa = bsum1024(dav, red);

    if (tid < BB) {                           // per-batch valid counts
        float s = 0.f;
        for (int j = 0; j < BPB; ++j)
            s += lo_f(aload64(&wsu[ST_U + (tid * BPB + j) * 4 + 3]));
        cntb8[tid] = s;
    }
    if (tid < BB * NB) allb[tid] = bins[tid];
    if (tid < BB * 82) {
        int ea = aloadi(&wsi[CA_I + tid]);
        int eb = aloadi(&wsi[CB_I + tid]);
        fA[tid] = (ea < 0) ? -INFINITY : __int_as_float(ea);
        fB[tid] = (eb < 0) ?  INFINITY : __int_as_float(0x7FFFFFFF - eb);
    }
    __syncthreads();
    if (tid < BB * NB) {
        int b2 = tid / NB, j = tid - b2 * NB;
        float v = allb[tid]; int r = 0;
        for (int k = 0; k < NB; ++k) { float u = allb[b2 * NB + k]; r += (u < v) || (u == v && k < j); }
        sbAll[b2 * NB + r] = v;
    }
    __syncthreads();

    if (tid < BB) {
        const float* SBb = &sbAll[tid * NB];
        bool anyInv = (cntb8[tid] != (float)HW);
        float rmin = anyInv ? pad : INFINITY;
        { float d = rmin - pad; tmpR[tid][81] = d * d; }
        for (int k = NB - 1; k >= 0; --k) {
            rmin = fminf(rmin, fB[tid * 82 + k + 1]);
            float d = rmin - SBb[k];
            tmpR[tid][k] = d * d;
        }
        float lmax = -INFINITY, sb = 0.f;
        for (int k = 0; k <= NB; ++k) {
            lmax = fmaxf(lmax, fA[tid * 82 + k]);
            float sk = (k < NB) ? SBb[k] : pad;
            float d = sk - lmax;
            sb += fminf(d * d, tmpR[tid][k]);
        }
        out8[tid] = sb;
    }
    __syncthreads();

    if (tid == 0) {
        float sumB = 0.f;
        for (int i = 0; i < BB; ++i) sumB += out8[i];
        float m1 = s0 / s3, m2 = s1 / s3;
        float silog = 10.0f * sqrtf(fmaxf(m2 - 0.85f * m1 * m1, 0.0f));
        float l2 = sqrtf(s2 / s3);
        float chamfer = (sa + sumB) / (float)BB;
        out[0] = l2 + silog + chamfer;
    }
}

// ---------------------------------------------------------------------------
extern "C" void kernel_launch(void* const* d_in, const int* in_sizes, int n_in,
                              void* d_out, int out_size, void* d_ws, size_t ws_size,
                              hipStream_t stream) {
    (void)in_sizes; (void)n_in; (void)out_size; (void)ws_size;
    const float* pred = (const float*)d_in[0];
    const float* tgt  = (const float*)d_in[1];
    const float* bins = (const float*)d_in[2];
    const void*  mask = d_in[3];
    float* ws  = (float*)d_ws;
    float* out = (float*)d_out;

    k_fused<<<NBLK, NTHR, 0, stream>>>(pred, tgt, bins, mask, ws, out);
}

// Round 9
// 23.438 us; speedup vs baseline: 1.9031x; 1.3921x over previous
//
#include <hip/hip_runtime.h>
#include <math.h>

// Problem constants
#define BB   8
#define NB   81
#define HW   76800
#define HW4  19200
#define EPS  1e-10f

#define BPB  19            // blocks per batch: 19*1024 = 19456 >= HW4
#define NBLK (BB * BPB)    // 152 blocks, 16 waves each — all co-resident
#define NTHR 1024
#define LUTN 512
#define MAGIC 0x5A5A5A5Au

typedef unsigned long long u64;

// ws u64 layout (checksum packs; poison/replay tolerant):
#define PT_U 0                     // [152] per-block maxT pack
#define ST_U 152                   // [152][4] sd, sd2, ssq, cnt packs
#define DA_U 760                   // [152] dirA pack (published last -> gate)
// int layout (from u64 index 912); idempotent monotone merges:
#define CA_I 1824                  // [8][82] max valid target, raw bits
#define CB_I 2480                  // [8][82] min valid target, enc 0x7FFFFFFF-bits

__device__ __forceinline__ u64 pack(float v) {
    unsigned b = __float_as_uint(v);
    return (u64)b | ((u64)(b ^ MAGIC) << 32);
}
__device__ __forceinline__ float spin_pair(const u64* slot) {   // wave-collective
    u64 v;
    for (;;) {
        v = __hip_atomic_load(slot, __ATOMIC_RELAXED, __HIP_MEMORY_SCOPE_AGENT);
        unsigned lo = (unsigned)v, hi = (unsigned)(v >> 32);
        if (__all((lo ^ MAGIC) == hi)) break;
        __builtin_amdgcn_s_sleep(1);
    }
    return __uint_as_float((unsigned)v);
}
__device__ __forceinline__ float lo_f(u64 v) { return __uint_as_float((unsigned)v); }
__device__ __forceinline__ u64 aload64(const u64* p) {
    return __hip_atomic_load(p, __ATOMIC_RELAXED, __HIP_MEMORY_SCOPE_AGENT);
}
__device__ __forceinline__ int aloadi(const int* p) {
    return __hip_atomic_load(p, __ATOMIC_RELAXED, __HIP_MEMORY_SCOPE_AGENT);
}

// full-wave (64) reductions, VALU-only
__device__ __forceinline__ float wsum(float v) {
#pragma unroll
    for (int o = 32; o > 0; o >>= 1) v += __shfl_xor(v, o, 64);
    return v;
}
__device__ __forceinline__ float wmax(float v) {
#pragma unroll
    for (int o = 32; o > 0; o >>= 1) v = fmaxf(v, __shfl_xor(v, o, 64));
    return v;
}
// 16-lane-group reductions (contiguous groups; xor 8/4/2/1 stays in group)
__device__ __forceinline__ float g16sum(float v) {
    v += __shfl_xor(v, 8, 64); v += __shfl_xor(v, 4, 64);
    v += __shfl_xor(v, 2, 64); v += __shfl_xor(v, 1, 64);
    return v;
}
__device__ __forceinline__ float g16max(float v) {
    v = fmaxf(v, __shfl_xor(v, 8, 64)); v = fmaxf(v, __shfl_xor(v, 4, 64));
    v = fmaxf(v, __shfl_xor(v, 2, 64)); v = fmaxf(v, __shfl_xor(v, 1, 64));
    return v;
}

__device__ __forceinline__ int probe_mode(const void* mask, int tid) {
    unsigned pv = ((const unsigned*)mask)[tid & 63];
    bool alli = __all(pv == 0u || pv == 1u);
    bool allf = __all(pv == 0u || pv == 0x3F800000u);
    return alli ? 1 : (allf ? 2 : 0);      // 1=int32, 2=float, 0=byte
}
__device__ __forceinline__ void mask4(const void* mask, int mode, int widx,
                                      int& m0, int& m1, int& m2, int& m3) {
    if (mode == 1)      { uint4  u = ((const uint4*) mask)[widx]; m0 = u.x; m1 = u.y; m2 = u.z; m3 = u.w; }
    else if (mode == 2) { float4 f = ((const float4*)mask)[widx]; m0 = f.x != 0.f; m1 = f.y != 0.f; m2 = f.z != 0.f; m3 = f.w != 0.f; }
    else { unsigned um = ((const unsigned*)mask)[widx];
           m0 = um & 0xFF; m1 = (um >> 8) & 0xFF; m2 = (um >> 16) & 0xFF; m3 = (um >> 24) & 0xFF; }
}

// ---------------------------------------------------------------------------
__global__ __launch_bounds__(NTHR, 1) void k_fused(const float* __restrict__ pred,
                                                   const float* __restrict__ tgt,
                                                   const float* __restrict__ bins,
                                                   const void*  __restrict__ mask,
                                                   float* __restrict__ ws,
                                                   float* __restrict__ out) {
    __shared__ float redw[16], redb[16];
    __shared__ float part[16][5];
    __shared__ float sraw[NB], ssrt[NB];
    __shared__ int   lut[LUTN];
    __shared__ int   iA[82], iB[82];
    __shared__ float s_maxB, s_rA, sred[5];
    // block-0 finalize scratch
    __shared__ float allb[BB * NB], sbAll[BB * NB];
    __shared__ float fA[BB * 82], fB[BB * 82];
    __shared__ float tmpR[BB][82];
    __shared__ float out8[BB], cntb8[BB];

    int tid = threadIdx.x, bid = blockIdx.x;
    int wid = tid >> 6, lane = tid & 63;
    int b = bid / BPB, c = bid - b * BPB;
    u64* wsu = (u64*)ws;
    int* wsi = (int*)ws;
    int mode = probe_mode(mask, tid);

    const int  idx  = c * NTHR + tid;       // exactly <=1 float4 per thread
    const bool live = (idx < HW4);
    const float4* p4p = (const float4*)(pred + (size_t)b * HW);
    const float4* t4p = (const float4*)(tgt  + (size_t)b * HW);

    // ---- loads (pred prefetched too: pad-independent) ----
    float4 t4 = make_float4(0.f, 0.f, 0.f, 0.f);
    float4 p4 = make_float4(0.f, 0.f, 0.f, 0.f);
    int m0 = 0, m1 = 0, m2 = 0, m3 = 0;
    if (live) {
        t4 = t4p[idx];
        p4 = p4p[idx];
        mask4(mask, mode, b * HW4 + idx, m0, m1, m2, m3);
    }

    // ---- phase 0: masked max(target); also stage bins ----
    float mt = 0.f;
    if (m0) mt = fmaxf(mt, t4.x);
    if (m1) mt = fmaxf(mt, t4.y);
    if (m2) mt = fmaxf(mt, t4.z);
    if (m3) mt = fmaxf(mt, t4.w);
    mt = wmax(mt);
    if (lane == 0) redw[wid] = mt;
    float bv = (tid < BB * NB) ? bins[tid] : -INFINITY;   // global maxB partial
    bv = wmax(bv);
    if (lane == 0) redb[wid] = bv;
    if (tid < NB) sraw[tid] = bins[b * NB + tid];
    __syncthreads();                                       // S1

    // publish this block's maxT (wave 0); reduce maxB (wave 1)
    if (tid < 16) {
        float v = g16max(redw[tid]);
        if (tid == 0) atomicExch(&wsu[PT_U + bid], pack(v));
    }
    if (tid >= 64 && tid < 80) {
        float v = g16max(redb[tid - 64]);
        if (tid == 64) s_maxB = v;
    }
    // rank-sort own batch's bins (pad-independent -> pre-barrier)
    if (tid < NB) {
        float v = sraw[tid]; int r = 0;
        for (int k = 0; k < NB; ++k) { float u = sraw[k]; r += (u < v) || (u == v && k < tid); }
        ssrt[r] = v;
    }
    if (tid < 82) { iA[tid] = 0xFF800000; iB[tid] = 0x7F800000; }
    __syncthreads();                                       // S2

    // LUT build (waves 0..7) BEFORE the spin so it overlaps waves 0..2 spinning
    float lo = ssrt[0], hi = ssrt[NB - 1];
    float w = (hi - lo) / (float)LUTN;
    float scale = (hi > lo) ? (float)LUTN / (hi - lo) : 0.f;
    if (tid < LUTN) {
        float edge = lo + (float)tid * w;
        int l = 0, r = NB;
        while (l < r) { int m = (l + r) >> 1; if (ssrt[m] < edge) l = m + 1; else r = m; }
        lut[tid] = l;
    }
    // ---- phase barrier: waves 0..2 spin on the 152 maxT packs ----
    float ptv = -INFINITY;
    if (tid < NBLK) ptv = spin_pair(&wsu[PT_U + tid]);
    ptv = wmax(ptv);
    if (lane == 0) redw[wid] = ptv;                        // waves 3.. write -inf, harmless
    __syncthreads();                                       // S3

    float maxT = redw[0];
#pragma unroll
    for (int k = 1; k < 16; ++k) maxT = fmaxf(maxT, redw[k]);
    float maxB = s_maxB;
    float mx = fmaxf(maxT, maxB), mn = fminf(maxT, maxB);
    float pad = mx + (mx - mn) + 1.0f;

    // ---- fused stats + chamfer (registers only; one float4 per thread) ----
    float sd = 0.f, sd2 = 0.f, ssq = 0.f, cnt = 0.f, dA = 0.f;
    if (live) {
        float pv_[4] = { p4.x, p4.y, p4.z, p4.w };
        float tv_[4] = { t4.x, t4.y, t4.z, t4.w };
        int   mv_[4] = { m0, m1, m2, m3 };
#pragma unroll
        for (int e = 0; e < 4; ++e) {
            if (!mv_[e]) continue;
            float t = tv_[e], p = pv_[e];
            float d = __logf((p + EPS) / (t + EPS));
            sd += d; sd2 += d * d;
            float er = p - t; ssq += er * er;
            cnt += 1.f;
            int q = (int)((t - lo) * scale);
            q = q < 0 ? 0 : (q > LUTN - 1 ? LUTN - 1 : q);
            int s = lut[q];
            while (s < NB && ssrt[s] <= t) ++s;
            while (s > 0 && ssrt[s - 1] > t) --s;
            float lof = (s > 0)  ? ssrt[s - 1] : -INFINITY;
            float hif = (s < NB) ? ssrt[s]     : pad;      // exact pad flank
            float dl = t - lof, dh = hif - t;
            dA += fminf(dl * dl, dh * dh);
            int bits = __float_as_int(t);
            atomicMax(&iA[s], bits);
            atomicMin(&iB[s], bits);
        }
    }
    // 5 reductions, one barrier
    sd = wsum(sd); sd2 = wsum(sd2); ssq = wsum(ssq); cnt = wsum(cnt); dA = wsum(dA);
    if (lane == 0) {
        part[wid][0] = sd; part[wid][1] = sd2; part[wid][2] = ssq;
        part[wid][3] = cnt; part[wid][4] = dA;
    }
    __syncthreads();                                       // S4 (iA/iB settled too)

    // global candidate merges (idempotent monotone)
    if (tid < 82) {
        int a = iA[tid], bm = iB[tid];
        if (a  != 0xFF800000) atomicMax(&wsi[CA_I + b * 82 + tid], a);
        if (bm != 0x7F800000) atomicMax(&wsi[CB_I + b * 82 + tid], 0x7FFFFFFF - bm);
    }
    // ST packs: 4 parallel group-leaders (wave 0); dirA reduced by wave 1
    if (tid < 64) {
        int q = tid >> 4, r = tid & 15;
        float v = g16sum(part[r][q]);
        if (r == 0) atomicExch(&wsu[ST_U + bid * 4 + q], pack(v));
    }
    if (tid >= 64 && tid < 80) {
        float v = g16sum(part[tid - 64][4]);
        if (tid == 64) s_rA = v;
    }
    // every wave drains its OWN vmem -> merges + ST at coherent point
    asm volatile("s_waitcnt vmcnt(0)" ::: "memory");
    __syncthreads();                                       // S5
    if (tid == 0) atomicExch(&wsu[DA_U + bid], pack(s_rA));  // gate + data

    if (bid != 0) return;

    // ================= Block 0: finalize =================
    float dav = 0.f, v0 = 0.f, v1 = 0.f, v2 = 0.f, v3 = 0.f;
    if (tid < NBLK) {
        dav = spin_pair(&wsu[DA_U + tid]);                 // gates ST + CA/CB
        v0 = lo_f(aload64(&wsu[ST_U + tid * 4 + 0]));
        v1 = lo_f(aload64(&wsu[ST_U + tid * 4 + 1]));
        v2 = lo_f(aload64(&wsu[ST_U + tid * 4 + 2]));
        v3 = lo_f(aload64(&wsu[ST_U + tid * 4 + 3]));
    }
    v0 = wsum(v0); v1 = wsum(v1); v2 = wsum(v2); v3 = wsum(v3); dav = wsum(dav);
    if (lane == 0) {
        part[wid][0] = v0; part[wid][1] = v1; part[wid][2] = v2;
        part[wid][3] = v3; part[wid][4] = dav;
    }
    if (tid < BB * NB) allb[tid] = bins[tid];
    __syncthreads();
    if (tid < 64) {
        int q = tid >> 4, r = tid & 15;
        float v = g16sum(part[r][q]);
        if (r == 0) sred[q] = v;
    }
    if (tid >= 64 && tid < 80) {
        float v = g16sum(part[tid - 64][4]);
        if (tid == 64) sred[4] = v;
    }
    if (tid < BB) {                                        // per-batch valid counts
        float s = 0.f;
        for (int j = 0; j < BPB; ++j)
            s += lo_f(aload64(&wsu[ST_U + (tid * BPB + j) * 4 + 3]));
        cntb8[tid] = s;
    }
    if (tid < BB * 82) {
        int ea = aloadi(&wsi[CA_I + tid]);
        int eb = aloadi(&wsi[CB_I + tid]);
        fA[tid] = (ea < 0) ? -INFINITY : __int_as_float(ea);
        fB[tid] = (eb < 0) ?  INFINITY : __int_as_float(0x7FFFFFFF - eb);
    }
    __syncthreads();
    if (tid < BB * NB) {                                   // sort all batches' bins
        int b2 = tid / NB, j = tid - b2 * NB;
        float v = allb[tid]; int r = 0;
        for (int k = 0; k < NB; ++k) { float u = allb[b2 * NB + k]; r += (u < v) || (u == v && k < j); }
        sbAll[b2 * NB + r] = v;
    }
    __syncthreads();

    if (tid < BB) {
        const float* SBb = &sbAll[tid * NB];
        bool anyInv = (cntb8[tid] != (float)HW);
        float rmin = anyInv ? pad : INFINITY;
        { float d = rmin - pad; tmpR[tid][81] = d * d; }
        for (int k = NB - 1; k >= 0; --k) {
            rmin = fminf(rmin, fB[tid * 82 + k + 1]);
            float d = rmin - SBb[k];
            tmpR[tid][k] = d * d;
        }
        float lmax = -INFINITY, sb = 0.f;
        for (int k = 0; k <= NB; ++k) {
            lmax = fmaxf(lmax, fA[tid * 82 + k]);
            float sk = (k < NB) ? SBb[k] : pad;
            float d = sk - lmax;
            sb += fminf(d * d, tmpR[tid][k]);
        }
        out8[tid] = sb;
    }
    __syncthreads();

    if (tid == 0) {
        float s0 = sred[0], s1 = sred[1], s2 = sred[2], s3 = sred[3], sa = sred[4];
        float sumB = 0.f;
        for (int i = 0; i < BB; ++i) sumB += out8[i];
        float m1 = s0 / s3, m2 = s1 / s3;
        float silog = 10.0f * sqrtf(fmaxf(m2 - 0.85f * m1 * m1, 0.0f));
        float l2 = sqrtf(s2 / s3);
        float chamfer = (sa + sumB) / (float)BB;
        out[0] = l2 + silog + chamfer;
    }
}

// ---------------------------------------------------------------------------
extern "C" void kernel_launch(void* const* d_in, const int* in_sizes, int n_in,
                              void* d_out, int out_size, void* d_ws, size_t ws_size,
                              hipStream_t stream) {
    (void)in_sizes; (void)n_in; (void)out_size; (void)ws_size;
    const float* pred = (const float*)d_in[0];
    const float* tgt  = (const float*)d_in[1];
    const float* bins = (const float*)d_in[2];
    const void*  mask = d_in[3];
    float* ws  = (float*)d_ws;
    float* out = (float*)d_out;

    k_fused<<<NBLK, NTHR, 0, stream>>>(pred, tgt, bins, mask, ws, out);
}